// Round 13
// baseline (508.078 us; speedup 1.0000x reference)
//
#include <hip/hip_runtime.h>
#include <hip/hip_bf16.h>
#include <hip/hip_cooperative_groups.h>

namespace cg = cooperative_groups;

typedef unsigned short ushort_t;
typedef __bf16 bf16_t;
typedef bf16_t bf16x8 __attribute__((ext_vector_type(8)));
typedef float f32x4 __attribute__((ext_vector_type(4)));
typedef float f32x16 __attribute__((ext_vector_type(16)));

#define CH 512
#define NSP 1024  // H*W

__device__ __forceinline__ float bf2f(ushort_t u) {
    union { unsigned int i; float f; } t; t.i = ((unsigned int)u) << 16; return t.f;
}
__device__ __forceinline__ ushort_t f2bf(float f) {
    union { float fl; unsigned int i; } t; t.fl = f;
    unsigned int r = t.i + 0x7fffu + ((t.i >> 16) & 1u);  // RNE
    return (ushort_t)(r >> 16);
}
// packed RNE f32x2 -> bf16x2 (v_cvt_pk_bf16_f32 on gfx950)
__device__ __forceinline__ unsigned int pk2(float a, float b) {
    __hip_bfloat162 h = __float22bfloat162_rn(make_float2(a, b));
    union { __hip_bfloat162 h2; unsigned int u; } t; t.h2 = h; return t.u;
}

#if __has_builtin(__builtin_amdgcn_global_load_lds)
#define HAVE_ASYNC_LDS 1
#endif
__device__ __forceinline__ void cp16(const ushort_t* g, ushort_t* l) {
#ifdef HAVE_ASYNC_LDS
    __builtin_amdgcn_global_load_lds((const __attribute__((address_space(1))) unsigned int*)g,
                                     (__attribute__((address_space(3))) unsigned int*)l, 16, 0, 0);
#else
    *(uint4*)l = *(const uint4*)g;
#endif
}

#if __has_builtin(__builtin_amdgcn_exp2f)
#define EXP2(x) __builtin_amdgcn_exp2f(x)
#else
#define EXP2(x) exp2f(x)
#endif

#define QSCALE 0.18033688011112042f   // 0.125 * log2(e), folded into q

#define Z16 {0.f,0.f,0.f,0.f,0.f,0.f,0.f,0.f,0.f,0.f,0.f,0.f,0.f,0.f,0.f,0.f}

#define PV_STEP(JS, P) {                                                                     \
    unsigned wA0 = pk2(P[((JS)&1)*8+0], P[((JS)&1)*8+1]);                                    \
    unsigned wA1 = pk2(P[((JS)&1)*8+2], P[((JS)&1)*8+3]);                                    \
    unsigned wB0 = pk2(P[((JS)&1)*8+4], P[((JS)&1)*8+5]);                                    \
    unsigned wB1 = pk2(P[((JS)&1)*8+6], P[((JS)&1)*8+7]);                                    \
    asm("v_permlane32_swap_b32 %0, %1" : "+v"(wA0), "+v"(wB0));                              \
    asm("v_permlane32_swap_b32 %0, %1" : "+v"(wA1), "+v"(wB1));                              \
    union { unsigned u[4]; bf16x8 v; } pa_;                                                  \
    pa_.u[0] = wA0; pa_.u[1] = wA1; pa_.u[2] = wB0; pa_.u[3] = wB1;                          \
    int phys_ = (((JS) * 2) | hi) ^ r7;                                                      \
    bf16x8 vf0 = *(const bf16x8*)(vbuf + l31 * 64 + phys_ * 8);                              \
    bf16x8 vf1 = *(const bf16x8*)(vbuf + (32 + l31) * 64 + phys_ * 8);                       \
    __builtin_amdgcn_s_setprio(1);                                                           \
    vacc0 = __builtin_amdgcn_mfma_f32_32x32x16_bf16(pa_.v, vf0, vacc0, 0, 0, 0);             \
    vacc1 = __builtin_amdgcn_mfma_f32_32x32x16_bf16(pa_.v, vf1, vacc1, 0, 0, 0);             \
    __builtin_amdgcn_s_setprio(0); }

// ==================== standalone kernels (R11-verified fallback path) =====================

__global__ __launch_bounds__(256) void prep_gn(const float* __restrict__ x, const float* __restrict__ gw,
                                               const float* __restrict__ gbias,
                                               const float* __restrict__ w0, const float* __restrict__ w1,
                                               const float* __restrict__ w2, const float* __restrict__ w3,
                                               ushort_t* __restrict__ wbf, ushort_t* __restrict__ xnt) {
    int tid = threadIdx.x;
    if (blockIdx.x >= 256) {
        int idx = (blockIdx.x - 256) * 256 + tid;
        int my = idx >> 16;
        const float* src = (my == 0) ? w0 : (my == 1) ? w1 : (my == 2) ? w2 : w3;
        float4 v = reinterpret_cast<const float4*>(src)[idx & 65535];
        uint2 u = make_uint2(pk2(v.x, v.y), pk2(v.z, v.w));
        reinterpret_cast<uint2*>(wbf + (size_t)my * 262144)[idx & 65535] = u;
        return;
    }
    __shared__ float red[8];
    int bg = blockIdx.x;
    int b = bg >> 5, g = bg & 31;
    const float4* x4 = reinterpret_cast<const float4*>(x + (size_t)bg * 16384);
    float4 v[16];
    float s = 0.f, s2 = 0.f;
    #pragma unroll
    for (int i = 0; i < 16; i++) {
        v[i] = x4[i * 256 + tid];
        s  += v[i].x + v[i].y + v[i].z + v[i].w;
        s2 += v[i].x * v[i].x + v[i].y * v[i].y + v[i].z * v[i].z + v[i].w * v[i].w;
    }
    #pragma unroll
    for (int off = 32; off > 0; off >>= 1) {
        s  += __shfl_down(s, off, 64);
        s2 += __shfl_down(s2, off, 64);
    }
    int wv = tid >> 6;
    if ((tid & 63) == 0) { red[wv] = s; red[4 + wv] = s2; }
    __syncthreads();
    float ts  = red[0] + red[1] + red[2] + red[3];
    float ts2 = red[4] + red[5] + red[6] + red[7];
    float mu  = ts * (1.f / 16384.f);
    float var = ts2 * (1.f / 16384.f) - mu * mu;
    float rstd = rsqrtf(var + 1e-5f);
    float ca[16], cb[16];
    #pragma unroll
    for (int cc = 0; cc < 16; cc++) {
        float ww = gw[g * 16 + cc], bb = gbias[g * 16 + cc];
        ca[cc] = rstd * ww; cb[cc] = bb - mu * ca[cc];
    }
    #pragma unroll
    for (int jj = 0; jj < 4; jj++) {
        float e[16];
        #pragma unroll
        for (int cc = 0; cc < 16; cc++) {
            float xv = (jj == 0) ? v[cc].x : (jj == 1) ? v[cc].y : (jj == 2) ? v[cc].z : v[cc].w;
            e[cc] = xv * ca[cc] + cb[cc];
        }
        uint4 u0 = make_uint4(pk2(e[0], e[1]), pk2(e[2], e[3]), pk2(e[4], e[5]), pk2(e[6], e[7]));
        uint4 u1 = make_uint4(pk2(e[8], e[9]), pk2(e[10], e[11]), pk2(e[12], e[13]), pk2(e[14], e[15]));
        ushort_t* dst = xnt + ((size_t)(b * 1024 + 4 * tid + jj)) * 512 + g * 16;
        *reinterpret_cast<uint4*>(dst)     = u0;
        *reinterpret_cast<uint4*>(dst + 8) = u1;
    }
}

__global__ __launch_bounds__(256) void conv_qkv(const ushort_t* __restrict__ xnt,
                                                const ushort_t* __restrict__ wbf,
                                                const float* __restrict__ bq,
                                                const float* __restrict__ bk,
                                                const float* __restrict__ bv,
                                                ushort_t* __restrict__ qt,
                                                ushort_t* __restrict__ kt,
                                                ushort_t* __restrict__ vt) {
    __shared__ __align__(16) char smem[17408];
    ushort_t* als = (ushort_t*)smem;
    ushort_t* bls = (ushort_t*)(smem + 8192);
    int tid = threadIdx.x;
    int wave = tid >> 6, lane = tid & 63, l15 = lane & 15, quad = lane >> 4;
    int wm = wave >> 1, wn = wave & 1;
    int m0 = blockIdx.x * 128, o0 = blockIdx.y * 64, b = blockIdx.z;
    const ushort_t* A = xnt + (size_t)b * 524288;

    f32x4 acc[4][2];
    #pragma unroll
    for (int ms = 0; ms < 4; ms++)
        #pragma unroll
        for (int ns = 0; ns < 2; ns++) acc[ms][ns] = (f32x4){0.f, 0.f, 0.f, 0.f};

    for (int k0 = 0; k0 < 512; k0 += 32) {
        #pragma unroll
        for (int rep = 0; rep < 2; rep++) {
            int id = rep * 256 + tid;
            int r = id >> 2, part = id & 3;
            int sw = part ^ ((r >> 2) & 3);
            cp16(A + (size_t)(m0 + r) * 512 + k0 + sw * 8, als + (size_t)id * 8);
        }
        {
            int r = tid >> 2, part = tid & 3;
            int sw = part ^ ((r >> 2) & 3);
            cp16(wbf + (size_t)(o0 + r) * 512 + k0 + sw * 8, bls + (size_t)tid * 8);
        }
        __syncthreads();
        bf16x8 af[4], bfr[2];
        #pragma unroll
        for (int ms = 0; ms < 4; ms++) {
            int row = wm * 64 + ms * 16 + l15;
            int slot = quad ^ ((row >> 2) & 3);
            af[ms] = *(const bf16x8*)(als + row * 32 + slot * 8);
        }
        #pragma unroll
        for (int ns = 0; ns < 2; ns++) {
            int row = wn * 32 + ns * 16 + l15;
            int slot = quad ^ ((row >> 2) & 3);
            bfr[ns] = *(const bf16x8*)(bls + row * 32 + slot * 8);
        }
        #pragma unroll
        for (int ms = 0; ms < 4; ms++)
            #pragma unroll
            for (int ns = 0; ns < 2; ns++)
                acc[ms][ns] = __builtin_amdgcn_mfma_f32_16x16x32_bf16(af[ms], bfr[ns], acc[ms][ns], 0, 0, 0);
        __syncthreads();
    }

    int seg = o0 >> 9, lo = o0 & 511;
    if (seg < 2) {
        const float* bias = seg ? bk : bq;
        ushort_t* dst = seg ? kt : qt;
        float s = seg ? 1.f : QSCALE;
        float bv0 = bias[lo + wn * 32 + l15];
        float bv1 = bias[lo + wn * 32 + 16 + l15];
        ushort_t* cls = (ushort_t*)smem;
        #pragma unroll
        for (int ms = 0; ms < 4; ms++)
            #pragma unroll
            for (int ns = 0; ns < 2; ns++) {
                float bb = ns ? bv1 : bv0;
                int idx = (wm * 64 + ms * 16 + quad * 4) * 64 + wn * 32 + ns * 16 + l15;
                unsigned int ua = pk2((acc[ms][ns][0] + bb) * s, (acc[ms][ns][1] + bb) * s);
                unsigned int ub = pk2((acc[ms][ns][2] + bb) * s, (acc[ms][ns][3] + bb) * s);
                cls[idx]       = (ushort_t)(ua & 0xffff);
                cls[idx + 64]  = (ushort_t)(ua >> 16);
                cls[idx + 128] = (ushort_t)(ub & 0xffff);
                cls[idx + 192] = (ushort_t)(ub >> 16);
            }
        __syncthreads();
        int h = lo >> 6;
        size_t obase = ((size_t)(b * 8 + h) * 1024 + m0) * 64;
        #pragma unroll
        for (int rep = 0; rep < 4; rep++) {
            int id = rep * 256 + tid;
            int r = id >> 3, part = id & 7;
            *(uint4*)(dst + obase + (size_t)r * 64 + part * 8) = *(const uint4*)(cls + r * 64 + part * 8);
        }
    } else {
        float bv0 = bv[lo + wn * 32 + l15];
        float bv1 = bv[lo + wn * 32 + 16 + l15];
        ushort_t* clst = (ushort_t*)smem;
        #pragma unroll
        for (int ms = 0; ms < 4; ms++)
            #pragma unroll
            for (int ns = 0; ns < 2; ns++) {
                float bb = ns ? bv1 : bv0;
                unsigned int ua = pk2(acc[ms][ns][0] + bb, acc[ms][ns][1] + bb);
                unsigned int ub = pk2(acc[ms][ns][2] + bb, acc[ms][ns][3] + bb);
                *(uint2*)(&clst[(wn * 32 + ns * 16 + l15) * 136 + wm * 64 + ms * 16 + quad * 4]) =
                    make_uint2(ua, ub);
            }
        __syncthreads();
        #pragma unroll
        for (int rep = 0; rep < 4; rep++) {
            int id = rep * 256 + tid;
            int row = id >> 4, part = id & 15;
            *(uint4*)(vt + ((size_t)(b * 512 + lo + row) * 1024 + m0 + part * 8)) =
                *(const uint4*)(clst + row * 136 + part * 8);
        }
    }
}

__global__ __launch_bounds__(256) void attn_kernel(const ushort_t* __restrict__ qt,
                                                   const ushort_t* __restrict__ kt,
                                                   const ushort_t* __restrict__ vt,
                                                   ushort_t* __restrict__ ao) {
    __shared__ __align__(16) ushort_t smem[16384];
    int tid = threadIdx.x;
    int wave = tid >> 6, lane = tid & 63, l31 = lane & 31, hi = lane >> 5;
    int id = blockIdx.x;
    int bh = (id & 7) * 8 + (id >> 6);
    int i0 = ((id >> 3) & 7) * 128;
    const ushort_t* qb = qt + (size_t)bh * 65536;
    const ushort_t* kb = kt + (size_t)bh * 65536;
    const ushort_t* vb = vt + (size_t)bh * 65536;
    int iw0 = i0 + wave * 32;
    int r7 = l31 & 7;

    bf16x8 qf[4];
    #pragma unroll
    for (int ks = 0; ks < 4; ks++)
        qf[ks] = *(const bf16x8*)(qb + (size_t)(iw0 + l31) * 64 + ks * 16 + hi * 8);

    f32x16 vacc0 = Z16, vacc1 = Z16;
    float lacc = 0.f;

    int rk0 = tid >> 3, sk = tid & 7, rk1 = rk0 + 32;
    const ushort_t* kg0 = kb + rk0 * 64 + (sk ^ (rk0 & 7)) * 8;
    const ushort_t* kg1 = kb + rk1 * 64 + (sk ^ (rk1 & 7)) * 8;
    const ushort_t* vg0 = vb + (size_t)rk0 * 1024 + (sk ^ (rk0 & 7)) * 8;
    const ushort_t* vg1 = vb + (size_t)rk1 * 1024 + (sk ^ (rk1 & 7)) * 8;

    cp16(kg0, smem + tid * 8);
    cp16(kg1, smem + (tid + 256) * 8);
    cp16(vg0, smem + 8192 + tid * 8);
    cp16(vg1, smem + 8192 + (tid + 256) * 8);
    kg0 += 4096; kg1 += 4096; vg0 += 64; vg1 += 64;
    __syncthreads();

    for (int jt = 0; jt < 16; jt++) {
        int cur = jt & 1;
        if (jt < 15) {
            ushort_t* kd = smem + (cur ^ 1) * 4096;
            ushort_t* vd = smem + 8192 + (cur ^ 1) * 4096;
            cp16(kg0, kd + tid * 8);
            cp16(kg1, kd + (tid + 256) * 8);
            cp16(vg0, vd + tid * 8);
            cp16(vg1, vd + (tid + 256) * 8);
            kg0 += 4096; kg1 += 4096; vg0 += 64; vg1 += 64;
        }
        const ushort_t* kbuf = smem + cur * 4096;
        const ushort_t* vbuf = smem + 8192 + cur * 4096;

        f32x16 s0 = Z16, s1 = Z16;
        __builtin_amdgcn_s_setprio(1);
        #pragma unroll
        for (int ks = 0; ks < 4; ks++) {
            int phys = ((ks * 2) | hi) ^ r7;
            bf16x8 kf = *(const bf16x8*)(kbuf + l31 * 64 + phys * 8);
            s0 = __builtin_amdgcn_mfma_f32_32x32x16_bf16(kf, qf[ks], s0, 0, 0, 0);
        }
        #pragma unroll
        for (int ks = 0; ks < 4; ks++) {
            int phys = ((ks * 2) | hi) ^ r7;
            bf16x8 kf = *(const bf16x8*)(kbuf + (32 + l31) * 64 + phys * 8);
            s1 = __builtin_amdgcn_mfma_f32_32x32x16_bf16(kf, qf[ks], s1, 0, 0, 0);
        }
        __builtin_amdgcn_s_setprio(0);

        float p0[16], p1[16];
        #pragma unroll
        for (int r = 0; r < 16; r++) p0[r] = EXP2(s0[r]);
        #pragma unroll
        for (int r = 0; r < 16; r++) p1[r] = EXP2(s1[r]);
        float t0 = 0.f, t1 = 0.f, t2 = 0.f, t3 = 0.f;
        #pragma unroll
        for (int r = 0; r < 4; r++) { t0 += p0[r]; t1 += p0[4 + r]; t2 += p0[8 + r]; t3 += p0[12 + r]; }
        #pragma unroll
        for (int r = 0; r < 4; r++) { t0 += p1[r]; t1 += p1[4 + r]; t2 += p1[8 + r]; t3 += p1[12 + r]; }
        lacc += (t0 + t1) + (t2 + t3);

        PV_STEP(0, p0)
        PV_STEP(1, p0)
        PV_STEP(2, p1)
        PV_STEP(3, p1)

        __syncthreads();
    }

    lacc += __shfl_xor(lacc, 32, 64);
    float linv[16];
    #pragma unroll
    for (int r = 0; r < 16; r++) {
        int ir = (r & 3) + 8 * (r >> 2) + 4 * hi;
        linv[r] = 1.f / __shfl(lacc, ir, 64);
    }

    ushort_t* ols = smem;
    #pragma unroll
    for (int r = 0; r < 16; r++) {
        int irow = wave * 32 + (r & 3) + 8 * (r >> 2) + 4 * hi;
        ols[irow * 80 + l31]      = f2bf(vacc0[r] * linv[r]);
        ols[irow * 80 + 32 + l31] = f2bf(vacc1[r] * linv[r]);
    }
    __syncthreads();
    int b = bh >> 3, h = bh & 7;
    ushort_t* aob = ao + ((size_t)b * 1024 + i0) * 512 + h * 64;
    #pragma unroll
    for (int rep = 0; rep < 4; rep++) {
        int idd = rep * 256 + tid;
        int rl = idd >> 3, part = idd & 7;
        *(uint4*)(aob + (size_t)rl * 512 + part * 8) = *(const uint4*)(ols + rl * 80 + part * 8);
    }
}

__global__ __launch_bounds__(256) void conv_out(const ushort_t* __restrict__ ao,
                                                const ushort_t* __restrict__ wo,
                                                const float* __restrict__ bo,
                                                const float* __restrict__ xres,
                                                float* __restrict__ out) {
    __shared__ __align__(16) char smem[12288];
    ushort_t* als = (ushort_t*)smem;
    ushort_t* bls = (ushort_t*)(smem + 8192);
    int tid = threadIdx.x;
    int wave = tid >> 6, lane = tid & 63, l15 = lane & 15, quad = lane >> 4;
    int wm = wave >> 1, wn = wave & 1;
    int m0 = blockIdx.x * 128, o0 = blockIdx.y * 64, b = blockIdx.z;
    const ushort_t* A = ao + (size_t)b * 524288;

    f32x4 acc[4][2];
    #pragma unroll
    for (int ms = 0; ms < 4; ms++)
        #pragma unroll
        for (int ns = 0; ns < 2; ns++) acc[ms][ns] = (f32x4){0.f, 0.f, 0.f, 0.f};

    for (int k0 = 0; k0 < 512; k0 += 32) {
        #pragma unroll
        for (int rep = 0; rep < 2; rep++) {
            int id = rep * 256 + tid;
            int r = id >> 2, part = id & 3;
            int sw = part ^ ((r >> 2) & 3);
            cp16(A + (size_t)(m0 + r) * 512 + k0 + sw * 8, als + (size_t)id * 8);
        }
        {
            int r = tid >> 2, part = tid & 3;
            int sw = part ^ ((r >> 2) & 3);
            cp16(wo + (size_t)(o0 + r) * 512 + k0 + sw * 8, bls + (size_t)tid * 8);
        }
        __syncthreads();
        bf16x8 af[4], bfr[2];
        #pragma unroll
        for (int ms = 0; ms < 4; ms++) {
            int row = wm * 64 + ms * 16 + l15;
            int slot = quad ^ ((row >> 2) & 3);
            af[ms] = *(const bf16x8*)(als + row * 32 + slot * 8);
        }
        #pragma unroll
        for (int ns = 0; ns < 2; ns++) {
            int row = wn * 32 + ns * 16 + l15;
            int slot = quad ^ ((row >> 2) & 3);
            bfr[ns] = *(const bf16x8*)(bls + row * 32 + slot * 8);
        }
        #pragma unroll
        for (int ms = 0; ms < 4; ms++)
            #pragma unroll
            for (int ns = 0; ns < 2; ns++)
                acc[ms][ns] = __builtin_amdgcn_mfma_f32_16x16x32_bf16(af[ms], bfr[ns], acc[ms][ns], 0, 0, 0);
        __syncthreads();
    }

    #pragma unroll
    for (int ns = 0; ns < 2; ns++) {
        int o = o0 + wn * 32 + ns * 16 + l15;
        float bb = bo[o];
        #pragma unroll
        for (int ms = 0; ms < 4; ms++) {
            int n = m0 + wm * 64 + ms * 16 + quad * 4;
            size_t ga = ((size_t)(b * 512 + o)) * 1024 + n;
            float4 xv = *(const float4*)(xres + ga);
            float4 c4;
            c4.x = acc[ms][ns][0] + bb + xv.x;
            c4.y = acc[ms][ns][1] + bb + xv.y;
            c4.z = acc[ms][ns][2] + bb + xv.z;
            c4.w = acc[ms][ns][3] + bb + xv.w;
            *(float4*)(out + ga) = c4;
        }
    }
}

// ==================== single cooperative kernel (512 blocks = 2/CU, validation-safe) ======
__global__ __launch_bounds__(256, 2) void fused_all(
    const float* __restrict__ x, const float* __restrict__ gnw, const float* __restrict__ gnb,
    const float* __restrict__ wq, const float* __restrict__ bq,
    const float* __restrict__ wk, const float* __restrict__ bk,
    const float* __restrict__ wv, const float* __restrict__ bv,
    const float* __restrict__ wo, const float* __restrict__ bo,
    ushort_t* __restrict__ xnt, ushort_t* __restrict__ qt, ushort_t* __restrict__ kt,
    ushort_t* __restrict__ vt, ushort_t* __restrict__ wbf, float* __restrict__ out)
{
    cg::grid_group grid = cg::this_grid();
    __shared__ __align__(16) char SMEM[32768];
    int tid = threadIdx.x;
    int bid = blockIdx.x;
    ushort_t* ao = xnt;   // attn output reuses xnt

    // ---------------- phase 0: fused GroupNorm (vb 0..255) + W fp32->bf16 (vb 256..1279) --
    for (int vb = bid; vb < 1280; vb += 512) {
        if (vb >= 256) {
            int idx = (vb - 256) * 256 + tid;
            int my = idx >> 16;
            const float* src = (my == 0) ? wq : (my == 1) ? wk : (my == 2) ? wv : wo;
            float4 v = reinterpret_cast<const float4*>(src)[idx & 65535];
            uint2 u = make_uint2(pk2(v.x, v.y), pk2(v.z, v.w));
            reinterpret_cast<uint2*>(wbf + (size_t)my * 262144)[idx & 65535] = u;
        } else {
            float* red = (float*)SMEM;
            int bg = vb, b = bg >> 5, g = bg & 31;
            const float4* x4 = reinterpret_cast<const float4*>(x + (size_t)bg * 16384);
            float4 v[16];
            float s = 0.f, s2 = 0.f;
            #pragma unroll
            for (int i = 0; i < 16; i++) {
                v[i] = x4[i * 256 + tid];
                s  += v[i].x + v[i].y + v[i].z + v[i].w;
                s2 += v[i].x * v[i].x + v[i].y * v[i].y + v[i].z * v[i].z + v[i].w * v[i].w;
            }
            #pragma unroll
            for (int off = 32; off > 0; off >>= 1) {
                s  += __shfl_down(s, off, 64);
                s2 += __shfl_down(s2, off, 64);
            }
            int wv_ = tid >> 6;
            if ((tid & 63) == 0) { red[wv_] = s; red[4 + wv_] = s2; }
            __syncthreads();
            float ts  = red[0] + red[1] + red[2] + red[3];
            float ts2 = red[4] + red[5] + red[6] + red[7];
            float mu  = ts * (1.f / 16384.f);
            float var = ts2 * (1.f / 16384.f) - mu * mu;
            float rstd = rsqrtf(var + 1e-5f);
            float ca[16], cb[16];
            #pragma unroll
            for (int cc = 0; cc < 16; cc++) {
                float ww = gnw[g * 16 + cc], bb = gnb[g * 16 + cc];
                ca[cc] = rstd * ww; cb[cc] = bb - mu * ca[cc];
            }
            #pragma unroll
            for (int jj = 0; jj < 4; jj++) {
                float e[16];
                #pragma unroll
                for (int cc = 0; cc < 16; cc++) {
                    float xv = (jj == 0) ? v[cc].x : (jj == 1) ? v[cc].y : (jj == 2) ? v[cc].z : v[cc].w;
                    e[cc] = xv * ca[cc] + cb[cc];
                }
                uint4 u0 = make_uint4(pk2(e[0], e[1]), pk2(e[2], e[3]), pk2(e[4], e[5]), pk2(e[6], e[7]));
                uint4 u1 = make_uint4(pk2(e[8], e[9]), pk2(e[10], e[11]), pk2(e[12], e[13]), pk2(e[14], e[15]));
                ushort_t* dst = xnt + ((size_t)(b * 1024 + 4 * tid + jj)) * 512 + g * 16;
                *reinterpret_cast<uint4*>(dst)     = u0;
                *reinterpret_cast<uint4*>(dst + 8) = u1;
            }
            __syncthreads();
        }
    }
    __threadfence();
    grid.sync();

    // ---------------- phase 1: conv_qkv, 1536 virtual tiles = 3 strides -------------------
    for (int vb = bid; vb < 1536; vb += 512) {
        int m0 = (vb & 7) * 128, o0 = ((vb >> 3) % 24) * 64, b = vb / 192;
        ushort_t* als = (ushort_t*)SMEM;
        ushort_t* bls = (ushort_t*)(SMEM + 8192);
        int wave = tid >> 6, lane = tid & 63, l15 = lane & 15, quad = lane >> 4;
        int wm = wave >> 1, wn = wave & 1;
        const ushort_t* A = xnt + (size_t)b * 524288;

        f32x4 acc[4][2];
        #pragma unroll
        for (int ms = 0; ms < 4; ms++)
            #pragma unroll
            for (int ns = 0; ns < 2; ns++) acc[ms][ns] = (f32x4){0.f, 0.f, 0.f, 0.f};

        __syncthreads();
        for (int k0 = 0; k0 < 512; k0 += 32) {
            #pragma unroll
            for (int rep = 0; rep < 2; rep++) {
                int id = rep * 256 + tid;
                int r = id >> 2, part = id & 3;
                int sw = part ^ ((r >> 2) & 3);
                cp16(A + (size_t)(m0 + r) * 512 + k0 + sw * 8, als + (size_t)id * 8);
            }
            {
                int r = tid >> 2, part = tid & 3;
                int sw = part ^ ((r >> 2) & 3);
                cp16(wbf + (size_t)(o0 + r) * 512 + k0 + sw * 8, bls + (size_t)tid * 8);
            }
            __syncthreads();
            bf16x8 af[4], bfr[2];
            #pragma unroll
            for (int ms = 0; ms < 4; ms++) {
                int row = wm * 64 + ms * 16 + l15;
                int slot = quad ^ ((row >> 2) & 3);
                af[ms] = *(const bf16x8*)(als + row * 32 + slot * 8);
            }
            #pragma unroll
            for (int ns = 0; ns < 2; ns++) {
                int row = wn * 32 + ns * 16 + l15;
                int slot = quad ^ ((row >> 2) & 3);
                bfr[ns] = *(const bf16x8*)(bls + row * 32 + slot * 8);
            }
            #pragma unroll
            for (int ms = 0; ms < 4; ms++)
                #pragma unroll
                for (int ns = 0; ns < 2; ns++)
                    acc[ms][ns] = __builtin_amdgcn_mfma_f32_16x16x32_bf16(af[ms], bfr[ns], acc[ms][ns], 0, 0, 0);
            __syncthreads();
        }

        int seg = o0 >> 9, lo = o0 & 511;
        if (seg < 2) {
            const float* bias = seg ? bk : bq;
            ushort_t* dst = seg ? kt : qt;
            float s = seg ? 1.f : QSCALE;
            float bv0 = bias[lo + wn * 32 + l15];
            float bv1 = bias[lo + wn * 32 + 16 + l15];
            ushort_t* cls = (ushort_t*)SMEM;
            #pragma unroll
            for (int ms = 0; ms < 4; ms++)
                #pragma unroll
                for (int ns = 0; ns < 2; ns++) {
                    float bb = ns ? bv1 : bv0;
                    int idx = (wm * 64 + ms * 16 + quad * 4) * 64 + wn * 32 + ns * 16 + l15;
                    unsigned int ua = pk2((acc[ms][ns][0] + bb) * s, (acc[ms][ns][1] + bb) * s);
                    unsigned int ub = pk2((acc[ms][ns][2] + bb) * s, (acc[ms][ns][3] + bb) * s);
                    cls[idx]       = (ushort_t)(ua & 0xffff);
                    cls[idx + 64]  = (ushort_t)(ua >> 16);
                    cls[idx + 128] = (ushort_t)(ub & 0xffff);
                    cls[idx + 192] = (ushort_t)(ub >> 16);
                }
            __syncthreads();
            int h = lo >> 6;
            size_t obase = ((size_t)(b * 8 + h) * 1024 + m0) * 64;
            #pragma unroll
            for (int rep = 0; rep < 4; rep++) {
                int id = rep * 256 + tid;
                int r = id >> 3, part = id & 7;
                *(uint4*)(dst + obase + (size_t)r * 64 + part * 8) = *(const uint4*)(cls + r * 64 + part * 8);
            }
        } else {
            float bv0 = bv[lo + wn * 32 + l15];
            float bv1 = bv[lo + wn * 32 + 16 + l15];
            ushort_t* clst = (ushort_t*)SMEM;
            #pragma unroll
            for (int ms = 0; ms < 4; ms++)
                #pragma unroll
                for (int ns = 0; ns < 2; ns++) {
                    float bb = ns ? bv1 : bv0;
                    unsigned int ua = pk2(acc[ms][ns][0] + bb, acc[ms][ns][1] + bb);
                    unsigned int ub = pk2(acc[ms][ns][2] + bb, acc[ms][ns][3] + bb);
                    *(uint2*)(&clst[(wn * 32 + ns * 16 + l15) * 136 + wm * 64 + ms * 16 + quad * 4]) =
                        make_uint2(ua, ub);
                }
            __syncthreads();
            #pragma unroll
            for (int rep = 0; rep < 4; rep++) {
                int id = rep * 256 + tid;
                int row = id >> 4, part = id & 15;
                *(uint4*)(vt + ((size_t)(b * 512 + lo + row) * 1024 + m0 + part * 8)) =
                    *(const uint4*)(clst + row * 136 + part * 8);
            }
        }
        __syncthreads();
    }
    __threadfence();
    grid.sync();

    // ---------------- phase 2: attn (R6 v2), 512 virtual blocks = 1 stride ----------------
    {
        ushort_t* smem = (ushort_t*)SMEM;
        int wave = tid >> 6, lane = tid & 63, l31 = lane & 31, hi = lane >> 5;
        int id = bid;
        int bh = (id & 7) * 8 + (id >> 6);
        int i0 = ((id >> 3) & 7) * 128;
        const ushort_t* qb = qt + (size_t)bh * 65536;
        const ushort_t* kb = kt + (size_t)bh * 65536;
        const ushort_t* vb2 = vt + (size_t)bh * 65536;
        int iw0 = i0 + wave * 32;
        int r7 = l31 & 7;

        bf16x8 qf[4];
        #pragma unroll
        for (int ks = 0; ks < 4; ks++)
            qf[ks] = *(const bf16x8*)(qb + (size_t)(iw0 + l31) * 64 + ks * 16 + hi * 8);

        f32x16 vacc0 = Z16, vacc1 = Z16;
        float lacc = 0.f;

        int rk0 = tid >> 3, sk = tid & 7, rk1 = rk0 + 32;
        const ushort_t* kg0 = kb + rk0 * 64 + (sk ^ (rk0 & 7)) * 8;
        const ushort_t* kg1 = kb + rk1 * 64 + (sk ^ (rk1 & 7)) * 8;
        const ushort_t* vg0 = vb2 + (size_t)rk0 * 1024 + (sk ^ (rk0 & 7)) * 8;
        const ushort_t* vg1 = vb2 + (size_t)rk1 * 1024 + (sk ^ (rk1 & 7)) * 8;

        cp16(kg0, smem + tid * 8);
        cp16(kg1, smem + (tid + 256) * 8);
        cp16(vg0, smem + 8192 + tid * 8);
        cp16(vg1, smem + 8192 + (tid + 256) * 8);
        kg0 += 4096; kg1 += 4096; vg0 += 64; vg1 += 64;
        __syncthreads();

        for (int jt = 0; jt < 16; jt++) {
            int cur = jt & 1;
            if (jt < 15) {
                ushort_t* kd = smem + (cur ^ 1) * 4096;
                ushort_t* vd = smem + 8192 + (cur ^ 1) * 4096;
                cp16(kg0, kd + tid * 8);
                cp16(kg1, kd + (tid + 256) * 8);
                cp16(vg0, vd + tid * 8);
                cp16(vg1, vd + (tid + 256) * 8);
                kg0 += 4096; kg1 += 4096; vg0 += 64; vg1 += 64;
            }
            const ushort_t* kbuf = smem + cur * 4096;
            const ushort_t* vbuf = smem + 8192 + cur * 4096;

            f32x16 s0 = Z16, s1 = Z16;
            __builtin_amdgcn_s_setprio(1);
            #pragma unroll
            for (int ks = 0; ks < 4; ks++) {
                int phys = ((ks * 2) | hi) ^ r7;
                bf16x8 kf = *(const bf16x8*)(kbuf + l31 * 64 + phys * 8);
                s0 = __builtin_amdgcn_mfma_f32_32x32x16_bf16(kf, qf[ks], s0, 0, 0, 0);
            }
            #pragma unroll
            for (int ks = 0; ks < 4; ks++) {
                int phys = ((ks * 2) | hi) ^ r7;
                bf16x8 kf = *(const bf16x8*)(kbuf + (32 + l31) * 64 + phys * 8);
                s1 = __builtin_amdgcn_mfma_f32_32x32x16_bf16(kf, qf[ks], s1, 0, 0, 0);
            }
            __builtin_amdgcn_s_setprio(0);

            float p0[16], p1[16];
            #pragma unroll
            for (int r = 0; r < 16; r++) p0[r] = EXP2(s0[r]);
            #pragma unroll
            for (int r = 0; r < 16; r++) p1[r] = EXP2(s1[r]);
            float t0 = 0.f, t1 = 0.f, t2 = 0.f, t3 = 0.f;
            #pragma unroll
            for (int r = 0; r < 4; r++) { t0 += p0[r]; t1 += p0[4 + r]; t2 += p0[8 + r]; t3 += p0[12 + r]; }
            #pragma unroll
            for (int r = 0; r < 4; r++) { t0 += p1[r]; t1 += p1[4 + r]; t2 += p1[8 + r]; t3 += p1[12 + r]; }
            lacc += (t0 + t1) + (t2 + t3);

            PV_STEP(0, p0)
            PV_STEP(1, p0)
            PV_STEP(2, p1)
            PV_STEP(3, p1)

            __syncthreads();
        }

        lacc += __shfl_xor(lacc, 32, 64);
        float linv[16];
        #pragma unroll
        for (int r = 0; r < 16; r++) {
            int ir = (r & 3) + 8 * (r >> 2) + 4 * hi;
            linv[r] = 1.f / __shfl(lacc, ir, 64);
        }

        ushort_t* ols = smem;
        #pragma unroll
        for (int r = 0; r < 16; r++) {
            int irow = wave * 32 + (r & 3) + 8 * (r >> 2) + 4 * hi;
            ols[irow * 80 + l31]      = f2bf(vacc0[r] * linv[r]);
            ols[irow * 80 + 32 + l31] = f2bf(vacc1[r] * linv[r]);
        }
        __syncthreads();
        int b = bh >> 3, h = bh & 7;
        ushort_t* aob = ao + ((size_t)b * 1024 + i0) * 512 + h * 64;
        #pragma unroll
        for (int rep = 0; rep < 4; rep++) {
            int idd = rep * 256 + tid;
            int rl = idd >> 3, part = idd & 7;
            *(uint4*)(aob + (size_t)rl * 512 + part * 8) = *(const uint4*)(ols + rl * 80 + part * 8);
        }
    }
    __threadfence();
    grid.sync();

    // ---------------- phase 3: conv_out, 512 virtual tiles = 1 stride ---------------------
    {
        int m0 = (bid & 7) * 128, o0 = ((bid >> 3) & 7) * 64, b = bid >> 6;
        ushort_t* als = (ushort_t*)SMEM;
        ushort_t* bls = (ushort_t*)(SMEM + 8192);
        const ushort_t* wob = wbf + 786432;
        int wave = tid >> 6, lane = tid & 63, l15 = lane & 15, quad = lane >> 4;
        int wm = wave >> 1, wn = wave & 1;
        const ushort_t* A = ao + (size_t)b * 524288;

        f32x4 acc[4][2];
        #pragma unroll
        for (int ms = 0; ms < 4; ms++)
            #pragma unroll
            for (int ns = 0; ns < 2; ns++) acc[ms][ns] = (f32x4){0.f, 0.f, 0.f, 0.f};

        __syncthreads();
        for (int k0 = 0; k0 < 512; k0 += 32) {
            #pragma unroll
            for (int rep = 0; rep < 2; rep++) {
                int id = rep * 256 + tid;
                int r = id >> 2, part = id & 3;
                int sw = part ^ ((r >> 2) & 3);
                cp16(A + (size_t)(m0 + r) * 512 + k0 + sw * 8, als + (size_t)id * 8);
            }
            {
                int r = tid >> 2, part = tid & 3;
                int sw = part ^ ((r >> 2) & 3);
                cp16(wob + (size_t)(o0 + r) * 512 + k0 + sw * 8, bls + (size_t)tid * 8);
            }
            __syncthreads();
            bf16x8 af[4], bfr[2];
            #pragma unroll
            for (int ms = 0; ms < 4; ms++) {
                int row = wm * 64 + ms * 16 + l15;
                int slot = quad ^ ((row >> 2) & 3);
                af[ms] = *(const bf16x8*)(als + row * 32 + slot * 8);
            }
            #pragma unroll
            for (int ns = 0; ns < 2; ns++) {
                int row = wn * 32 + ns * 16 + l15;
                int slot = quad ^ ((row >> 2) & 3);
                bfr[ns] = *(const bf16x8*)(bls + row * 32 + slot * 8);
            }
            #pragma unroll
            for (int ms = 0; ms < 4; ms++)
                #pragma unroll
                for (int ns = 0; ns < 2; ns++)
                    acc[ms][ns] = __builtin_amdgcn_mfma_f32_16x16x32_bf16(af[ms], bfr[ns], acc[ms][ns], 0, 0, 0);
            __syncthreads();
        }

        #pragma unroll
        for (int ns = 0; ns < 2; ns++) {
            int o = o0 + wn * 32 + ns * 16 + l15;
            float bb = bo[o];
            #pragma unroll
            for (int ms = 0; ms < 4; ms++) {
                int n = m0 + wm * 64 + ms * 16 + quad * 4;
                size_t ga = ((size_t)(b * 512 + o)) * 1024 + n;
                float4 xv = *(const float4*)(x + ga);
                float4 c4;
                c4.x = acc[ms][ns][0] + bb + xv.x;
                c4.y = acc[ms][ns][1] + bb + xv.y;
                c4.z = acc[ms][ns][2] + bb + xv.z;
                c4.w = acc[ms][ns][3] + bb + xv.w;
                *(float4*)(out + ga) = c4;
            }
        }
    }
}

extern "C" void kernel_launch(void* const* d_in, const int* in_sizes, int n_in,
                              void* d_out, int out_size, void* d_ws, size_t ws_size,
                              hipStream_t stream) {
    const float* x    = (const float*)d_in[0];
    const float* gn_w = (const float*)d_in[1];
    const float* gn_b = (const float*)d_in[2];
    const float* wq   = (const float*)d_in[3];
    const float* bq   = (const float*)d_in[4];
    const float* wk   = (const float*)d_in[5];
    const float* bk   = (const float*)d_in[6];
    const float* wv   = (const float*)d_in[7];
    const float* bv   = (const float*)d_in[8];
    const float* wo   = (const float*)d_in[9];
    const float* bo   = (const float*)d_in[10];

    char* ws = (char*)d_ws;
    ushort_t* xnt  = (ushort_t*)(ws);                        // 8 MB  [b][n][c]
    ushort_t* qt   = (ushort_t*)(ws + (((size_t)8)  << 20)); // 8 MB  [bh][n][d] (pre-scaled)
    ushort_t* kt   = (ushort_t*)(ws + (((size_t)16) << 20)); // 8 MB  [bh][n][d]
    ushort_t* vt   = (ushort_t*)(ws + (((size_t)24) << 20)); // 8 MB  [b][c][n]
    ushort_t* wbf  = (ushort_t*)(ws + (((size_t)32) << 20)); // 2 MB  Wq|Wk|Wv|Wo bf16
    float* outp = (float*)d_out;
    ushort_t* ao = xnt;

    void* args[] = {
        (void*)&x, (void*)&gn_w, (void*)&gn_b,
        (void*)&wq, (void*)&bq, (void*)&wk, (void*)&bk,
        (void*)&wv, (void*)&bv, (void*)&wo, (void*)&bo,
        (void*)&xnt, (void*)&qt, (void*)&kt, (void*)&vt, (void*)&wbf, (void*)&outp
    };
    hipError_t err = hipLaunchCooperativeKernel((void*)fused_all, dim3(512), dim3(256),
                                                args, 0, stream);
    if (err != hipSuccess) {
        // fallback: R11-verified 4-kernel path
        prep_gn<<<1280, 256, 0, stream>>>(x, gn_w, gn_b, wq, wk, wv, wo, wbf, xnt);
        conv_qkv<<<dim3(8, 24, 8), 256, 0, stream>>>(xnt, wbf, bq, bk, bv, qt, kt, vt);
        attn_kernel<<<512, 256, 0, stream>>>(qt, kt, vt, ao);
        conv_out<<<dim3(8, 8, 8), 256, 0, stream>>>(ao, wbf + 786432, bo, x, outp);
    }
}

// Round 14
// 268.623 us; speedup vs baseline: 1.8914x; 1.8914x over previous
//
#include <hip/hip_runtime.h>
#include <hip/hip_bf16.h>

typedef unsigned short ushort_t;
typedef __bf16 bf16_t;
typedef bf16_t bf16x8 __attribute__((ext_vector_type(8)));
typedef float f32x4 __attribute__((ext_vector_type(4)));
typedef float f32x16 __attribute__((ext_vector_type(16)));

#define CH 512
#define NSP 1024  // H*W

__device__ __forceinline__ float bf2f(ushort_t u) {
    union { unsigned int i; float f; } t; t.i = ((unsigned int)u) << 16; return t.f;
}
__device__ __forceinline__ ushort_t f2bf(float f) {
    union { float fl; unsigned int i; } t; t.fl = f;
    unsigned int r = t.i + 0x7fffu + ((t.i >> 16) & 1u);  // RNE
    return (ushort_t)(r >> 16);
}
// packed RNE f32x2 -> bf16x2 (v_cvt_pk_bf16_f32 on gfx950)
__device__ __forceinline__ unsigned int pk2(float a, float b) {
    __hip_bfloat162 h = __float22bfloat162_rn(make_float2(a, b));
    union { __hip_bfloat162 h2; unsigned int u; } t; t.h2 = h; return t.u;
}

#if __has_builtin(__builtin_amdgcn_global_load_lds)
#define HAVE_ASYNC_LDS 1
#endif
__device__ __forceinline__ void cp16(const ushort_t* g, ushort_t* l) {
#ifdef HAVE_ASYNC_LDS
    __builtin_amdgcn_global_load_lds((const __attribute__((address_space(1))) unsigned int*)g,
                                     (__attribute__((address_space(3))) unsigned int*)l, 16, 0, 0);
#else
    *(uint4*)l = *(const uint4*)g;
#endif
}

#if __has_builtin(__builtin_amdgcn_exp2f)
#define EXP2(x) __builtin_amdgcn_exp2f(x)
#else
#define EXP2(x) exp2f(x)
#endif

#define QSCALE 0.18033688011112042f   // 0.125 * log2(e), folded into q

#define Z16 {0.f,0.f,0.f,0.f,0.f,0.f,0.f,0.f,0.f,0.f,0.f,0.f,0.f,0.f,0.f,0.f}

#define PV_STEP(JS, P) {                                                                     \
    unsigned wA0 = pk2(P[((JS)&1)*8+0], P[((JS)&1)*8+1]);                                    \
    unsigned wA1 = pk2(P[((JS)&1)*8+2], P[((JS)&1)*8+3]);                                    \
    unsigned wB0 = pk2(P[((JS)&1)*8+4], P[((JS)&1)*8+5]);                                    \
    unsigned wB1 = pk2(P[((JS)&1)*8+6], P[((JS)&1)*8+7]);                                    \
    asm("v_permlane32_swap_b32 %0, %1" : "+v"(wA0), "+v"(wB0));                              \
    asm("v_permlane32_swap_b32 %0, %1" : "+v"(wA1), "+v"(wB1));                              \
    union { unsigned u[4]; bf16x8 v; } pa_;                                                  \
    pa_.u[0] = wA0; pa_.u[1] = wA1; pa_.u[2] = wB0; pa_.u[3] = wB1;                          \
    int phys_ = (((JS) * 2) | hi) ^ r7;                                                      \
    bf16x8 vf0 = *(const bf16x8*)(vbuf + l31 * 64 + phys_ * 8);                              \
    bf16x8 vf1 = *(const bf16x8*)(vbuf + (32 + l31) * 64 + phys_ * 8);                       \
    __builtin_amdgcn_s_setprio(1);                                                           \
    vacc0 = __builtin_amdgcn_mfma_f32_32x32x16_bf16(pa_.v, vf0, vacc0, 0, 0, 0);             \
    vacc1 = __builtin_amdgcn_mfma_f32_32x32x16_bf16(pa_.v, vf1, vacc1, 0, 0, 0);             \
    __builtin_amdgcn_s_setprio(0); }

// ---------------- prep_gn: blocks 0..255 = fused GroupNorm; 256..1279 = W fp32->bf16 ------
// Also zeroes the 64 producer-consumer counters used by attn_out.
__global__ __launch_bounds__(256) void prep_gn(const float* __restrict__ x, const float* __restrict__ gw,
                                               const float* __restrict__ gbias,
                                               const float* __restrict__ w0, const float* __restrict__ w1,
                                               const float* __restrict__ w2, const float* __restrict__ w3,
                                               ushort_t* __restrict__ wbf, ushort_t* __restrict__ xnt,
                                               int* __restrict__ cnt) {
    int tid = threadIdx.x;
    if (blockIdx.x == 0 && tid < 64) cnt[tid] = 0;
    if (blockIdx.x >= 256) {
        int idx = (blockIdx.x - 256) * 256 + tid;
        int my = idx >> 16;
        const float* src = (my == 0) ? w0 : (my == 1) ? w1 : (my == 2) ? w2 : w3;
        float4 v = reinterpret_cast<const float4*>(src)[idx & 65535];
        uint2 u = make_uint2(pk2(v.x, v.y), pk2(v.z, v.w));
        reinterpret_cast<uint2*>(wbf + (size_t)my * 262144)[idx & 65535] = u;
        return;
    }
    __shared__ float red[8];
    int bg = blockIdx.x;
    int b = bg >> 5, g = bg & 31;
    const float4* x4 = reinterpret_cast<const float4*>(x + (size_t)bg * 16384);
    float4 v[16];
    float s = 0.f, s2 = 0.f;
    #pragma unroll
    for (int i = 0; i < 16; i++) {
        v[i] = x4[i * 256 + tid];
        s  += v[i].x + v[i].y + v[i].z + v[i].w;
        s2 += v[i].x * v[i].x + v[i].y * v[i].y + v[i].z * v[i].z + v[i].w * v[i].w;
    }
    #pragma unroll
    for (int off = 32; off > 0; off >>= 1) {
        s  += __shfl_down(s, off, 64);
        s2 += __shfl_down(s2, off, 64);
    }
    int wv = tid >> 6;
    if ((tid & 63) == 0) { red[wv] = s; red[4 + wv] = s2; }
    __syncthreads();
    float ts  = red[0] + red[1] + red[2] + red[3];
    float ts2 = red[4] + red[5] + red[6] + red[7];
    float mu  = ts * (1.f / 16384.f);
    float var = ts2 * (1.f / 16384.f) - mu * mu;
    float rstd = rsqrtf(var + 1e-5f);
    float ca[16], cb[16];
    #pragma unroll
    for (int cc = 0; cc < 16; cc++) {
        float ww = gw[g * 16 + cc], bb = gbias[g * 16 + cc];
        ca[cc] = rstd * ww; cb[cc] = bb - mu * ca[cc];
    }
    #pragma unroll
    for (int jj = 0; jj < 4; jj++) {
        float e[16];
        #pragma unroll
        for (int cc = 0; cc < 16; cc++) {
            float xv = (jj == 0) ? v[cc].x : (jj == 1) ? v[cc].y : (jj == 2) ? v[cc].z : v[cc].w;
            e[cc] = xv * ca[cc] + cb[cc];
        }
        uint4 u0 = make_uint4(pk2(e[0], e[1]), pk2(e[2], e[3]), pk2(e[4], e[5]), pk2(e[6], e[7]));
        uint4 u1 = make_uint4(pk2(e[8], e[9]), pk2(e[10], e[11]), pk2(e[12], e[13]), pk2(e[14], e[15]));
        ushort_t* dst = xnt + ((size_t)(b * 1024 + 4 * tid + jj)) * 512 + g * 16;
        *reinterpret_cast<uint4*>(dst)     = u0;
        *reinterpret_cast<uint4*>(dst + 8) = u1;
    }
}

// ---------------- Fused QKV conv (R1 v1): C[n_sp(128)][o(64)] tiles -----------------------
__global__ __launch_bounds__(256) void conv_qkv(const ushort_t* __restrict__ xnt,
                                                const ushort_t* __restrict__ wbf,
                                                const float* __restrict__ bq,
                                                const float* __restrict__ bk,
                                                const float* __restrict__ bv,
                                                ushort_t* __restrict__ qt,
                                                ushort_t* __restrict__ kt,
                                                ushort_t* __restrict__ vt) {
    __shared__ __align__(16) char smem[17408];
    ushort_t* als = (ushort_t*)smem;
    ushort_t* bls = (ushort_t*)(smem + 8192);
    int tid = threadIdx.x;
    int wave = tid >> 6, lane = tid & 63, l15 = lane & 15, quad = lane >> 4;
    int wm = wave >> 1, wn = wave & 1;
    int m0 = blockIdx.x * 128, o0 = blockIdx.y * 64, b = blockIdx.z;
    const ushort_t* A = xnt + (size_t)b * 524288;

    f32x4 acc[4][2];
    #pragma unroll
    for (int ms = 0; ms < 4; ms++)
        #pragma unroll
        for (int ns = 0; ns < 2; ns++) acc[ms][ns] = (f32x4){0.f, 0.f, 0.f, 0.f};

    for (int k0 = 0; k0 < 512; k0 += 32) {
        #pragma unroll
        for (int rep = 0; rep < 2; rep++) {
            int id = rep * 256 + tid;
            int r = id >> 2, part = id & 3;
            int sw = part ^ ((r >> 2) & 3);
            cp16(A + (size_t)(m0 + r) * 512 + k0 + sw * 8, als + (size_t)id * 8);
        }
        {
            int r = tid >> 2, part = tid & 3;
            int sw = part ^ ((r >> 2) & 3);
            cp16(wbf + (size_t)(o0 + r) * 512 + k0 + sw * 8, bls + (size_t)tid * 8);
        }
        __syncthreads();
        bf16x8 af[4], bfr[2];
        #pragma unroll
        for (int ms = 0; ms < 4; ms++) {
            int row = wm * 64 + ms * 16 + l15;
            int slot = quad ^ ((row >> 2) & 3);
            af[ms] = *(const bf16x8*)(als + row * 32 + slot * 8);
        }
        #pragma unroll
        for (int ns = 0; ns < 2; ns++) {
            int row = wn * 32 + ns * 16 + l15;
            int slot = quad ^ ((row >> 2) & 3);
            bfr[ns] = *(const bf16x8*)(bls + row * 32 + slot * 8);
        }
        #pragma unroll
        for (int ms = 0; ms < 4; ms++)
            #pragma unroll
            for (int ns = 0; ns < 2; ns++)
                acc[ms][ns] = __builtin_amdgcn_mfma_f32_16x16x32_bf16(af[ms], bfr[ns], acc[ms][ns], 0, 0, 0);
        __syncthreads();
    }

    int seg = o0 >> 9, lo = o0 & 511;
    if (seg < 2) {
        const float* bias = seg ? bk : bq;
        ushort_t* dst = seg ? kt : qt;
        float s = seg ? 1.f : QSCALE;
        float bv0 = bias[lo + wn * 32 + l15];
        float bv1 = bias[lo + wn * 32 + 16 + l15];
        ushort_t* cls = (ushort_t*)smem;
        #pragma unroll
        for (int ms = 0; ms < 4; ms++)
            #pragma unroll
            for (int ns = 0; ns < 2; ns++) {
                float bb = ns ? bv1 : bv0;
                int idx = (wm * 64 + ms * 16 + quad * 4) * 64 + wn * 32 + ns * 16 + l15;
                unsigned int ua = pk2((acc[ms][ns][0] + bb) * s, (acc[ms][ns][1] + bb) * s);
                unsigned int ub = pk2((acc[ms][ns][2] + bb) * s, (acc[ms][ns][3] + bb) * s);
                cls[idx]       = (ushort_t)(ua & 0xffff);
                cls[idx + 64]  = (ushort_t)(ua >> 16);
                cls[idx + 128] = (ushort_t)(ub & 0xffff);
                cls[idx + 192] = (ushort_t)(ub >> 16);
            }
        __syncthreads();
        int h = lo >> 6;
        size_t obase = ((size_t)(b * 8 + h) * 1024 + m0) * 64;
        #pragma unroll
        for (int rep = 0; rep < 4; rep++) {
            int id = rep * 256 + tid;
            int r = id >> 3, part = id & 7;
            *(uint4*)(dst + obase + (size_t)r * 64 + part * 8) = *(const uint4*)(cls + r * 64 + part * 8);
        }
    } else {
        float bv0 = bv[lo + wn * 32 + l15];
        float bv1 = bv[lo + wn * 32 + 16 + l15];
        ushort_t* clst = (ushort_t*)smem;
        #pragma unroll
        for (int ms = 0; ms < 4; ms++)
            #pragma unroll
            for (int ns = 0; ns < 2; ns++) {
                float bb = ns ? bv1 : bv0;
                unsigned int ua = pk2(acc[ms][ns][0] + bb, acc[ms][ns][1] + bb);
                unsigned int ub = pk2(acc[ms][ns][2] + bb, acc[ms][ns][3] + bb);
                *(uint2*)(&clst[(wn * 32 + ns * 16 + l15) * 136 + wm * 64 + ms * 16 + quad * 4]) =
                    make_uint2(ua, ub);
            }
        __syncthreads();
        #pragma unroll
        for (int rep = 0; rep < 4; rep++) {
            int id = rep * 256 + tid;
            int row = id >> 4, part = id & 15;
            *(uint4*)(vt + ((size_t)(b * 512 + lo + row) * 1024 + m0 + part * 8)) =
                *(const uint4*)(clst + row * 136 + part * 8);
        }
    }
}

// ---------------- attn_out: R11 attn (counted-vmcnt) + fused conv_out via per-group sync --
// 512 blocks (2/CU, 48KB LDS -> max 3/CU => all co-resident, spin is safe).
// Group g = (b, i0): 8 blocks (h=0..7). After attn each block fences + atomicAdd(cnt[g]);
// waits for 8; then computes conv_out tile (b, m0=i0, o0=h*64) = exact old conv_out grid.
__global__ __launch_bounds__(256) void attn_out(const ushort_t* __restrict__ qt,
                                                const ushort_t* __restrict__ kt,
                                                const ushort_t* __restrict__ vt,
                                                ushort_t* __restrict__ ao,
                                                const ushort_t* __restrict__ wo,
                                                const float* __restrict__ bo,
                                                const float* __restrict__ xres,
                                                float* __restrict__ out,
                                                int* __restrict__ cnt) {
    __shared__ __align__(16) ushort_t smem[24576];   // 48 KB: K[3][4096] | V[3][4096]
    int tid = threadIdx.x;
    int wave = tid >> 6, lane = tid & 63, l31 = lane & 31, hi = lane >> 5;
    int id = blockIdx.x;                 // XCD-swizzled
    int bh = (id & 7) * 8 + (id >> 6);
    int i0 = ((id >> 3) & 7) * 128;
    const ushort_t* qb = qt + (size_t)bh * 65536;
    const ushort_t* kb = kt + (size_t)bh * 65536;
    const ushort_t* vb = vt + (size_t)bh * 65536;
    int iw0 = i0 + wave * 32;
    int r7 = l31 & 7;

    bf16x8 qf[4];
    #pragma unroll
    for (int ks = 0; ks < 4; ks++)
        qf[ks] = *(const bf16x8*)(qb + (size_t)(iw0 + l31) * 64 + ks * 16 + hi * 8);

    f32x16 vacc0 = Z16, vacc1 = Z16;
    float lacc = 0.f;

    int rk0 = tid >> 3, sk = tid & 7, rk1 = rk0 + 32;
    const ushort_t* kg0 = kb + rk0 * 64 + (sk ^ (rk0 & 7)) * 8;
    const ushort_t* kg1 = kb + rk1 * 64 + (sk ^ (rk1 & 7)) * 8;
    const ushort_t* vg0 = vb + (size_t)rk0 * 1024 + (sk ^ (rk0 & 7)) * 8;
    const ushort_t* vg1 = vb + (size_t)rk1 * 1024 + (sk ^ (rk1 & 7)) * 8;

    // prologue: tile 0 -> buf0, tile 1 -> buf1 (8 loads in flight)
    cp16(kg0, smem + tid * 8);
    cp16(kg1, smem + (tid + 256) * 8);
    cp16(vg0, smem + 12288 + tid * 8);
    cp16(vg1, smem + 12288 + (tid + 256) * 8);
    kg0 += 4096; kg1 += 4096; vg0 += 64; vg1 += 64;
    cp16(kg0, smem + 4096 + tid * 8);
    cp16(kg1, smem + 4096 + (tid + 256) * 8);
    cp16(vg0, smem + 16384 + tid * 8);
    cp16(vg1, smem + 16384 + (tid + 256) * 8);
    kg0 += 4096; kg1 += 4096; vg0 += 64; vg1 += 64;

    for (int jt = 0; jt < 16; jt++) {
        if (jt == 15) asm volatile("s_waitcnt vmcnt(0)" ::: "memory");
        else          asm volatile("s_waitcnt vmcnt(4)" ::: "memory");
        __builtin_amdgcn_s_barrier();
        __builtin_amdgcn_sched_barrier(0);
        if (jt < 14) {
            int nb = jt + 2 - ((jt + 2) >= 3 ? 3 : 0) - ((jt + 2) >= 6 ? 3 : 0)
                     - ((jt + 2) >= 9 ? 3 : 0) - ((jt + 2) >= 12 ? 3 : 0) - ((jt + 2) >= 15 ? 3 : 0);
            ushort_t* kd = smem + nb * 4096;
            ushort_t* vd = smem + 12288 + nb * 4096;
            cp16(kg0, kd + tid * 8);
            cp16(kg1, kd + (tid + 256) * 8);
            cp16(vg0, vd + tid * 8);
            cp16(vg1, vd + (tid + 256) * 8);
            kg0 += 4096; kg1 += 4096; vg0 += 64; vg1 += 64;
        }
        int cur = jt - (jt >= 3 ? 3 : 0) - (jt >= 6 ? 3 : 0) - (jt >= 9 ? 3 : 0)
                  - (jt >= 12 ? 3 : 0) - (jt >= 15 ? 3 : 0);
        const ushort_t* kbuf = smem + cur * 4096;
        const ushort_t* vbuf = smem + 12288 + cur * 4096;

        f32x16 s0 = Z16, s1 = Z16;
        __builtin_amdgcn_s_setprio(1);
        #pragma unroll
        for (int ks = 0; ks < 4; ks++) {
            int phys = ((ks * 2) | hi) ^ r7;
            bf16x8 kf = *(const bf16x8*)(kbuf + l31 * 64 + phys * 8);
            s0 = __builtin_amdgcn_mfma_f32_32x32x16_bf16(kf, qf[ks], s0, 0, 0, 0);
        }
        #pragma unroll
        for (int ks = 0; ks < 4; ks++) {
            int phys = ((ks * 2) | hi) ^ r7;
            bf16x8 kf = *(const bf16x8*)(kbuf + (32 + l31) * 64 + phys * 8);
            s1 = __builtin_amdgcn_mfma_f32_32x32x16_bf16(kf, qf[ks], s1, 0, 0, 0);
        }
        __builtin_amdgcn_s_setprio(0);

        float p0[16], p1[16];
        #pragma unroll
        for (int r = 0; r < 16; r++) p0[r] = EXP2(s0[r]);
        #pragma unroll
        for (int r = 0; r < 16; r++) p1[r] = EXP2(s1[r]);
        float t0 = 0.f, t1 = 0.f, t2 = 0.f, t3 = 0.f;
        #pragma unroll
        for (int r = 0; r < 4; r++) { t0 += p0[r]; t1 += p0[4 + r]; t2 += p0[8 + r]; t3 += p0[12 + r]; }
        #pragma unroll
        for (int r = 0; r < 4; r++) { t0 += p1[r]; t1 += p1[4 + r]; t2 += p1[8 + r]; t3 += p1[12 + r]; }
        lacc += (t0 + t1) + (t2 + t3);

        PV_STEP(0, p0)
        PV_STEP(1, p0)
        PV_STEP(2, p1)
        PV_STEP(3, p1)
    }

    __syncthreads();   // all waves done reading LDS buffers before epilogue reuse

    lacc += __shfl_xor(lacc, 32, 64);
    float linv[16];
    #pragma unroll
    for (int r = 0; r < 16; r++) {
        int ir = (r & 3) + 8 * (r >> 2) + 4 * hi;
        linv[r] = 1.f / __shfl(lacc, ir, 64);
    }

    ushort_t* ols = smem;
    #pragma unroll
    for (int r = 0; r < 16; r++) {
        int irow = wave * 32 + (r & 3) + 8 * (r >> 2) + 4 * hi;
        ols[irow * 80 + l31]      = f2bf(vacc0[r] * linv[r]);
        ols[irow * 80 + 32 + l31] = f2bf(vacc1[r] * linv[r]);
    }
    __syncthreads();
    int b = bh >> 3, h = bh & 7;
    ushort_t* aob = ao + ((size_t)b * 1024 + i0) * 512 + h * 64;
    #pragma unroll
    for (int rep = 0; rep < 4; rep++) {
        int idd = rep * 256 + tid;
        int rl = idd >> 3, part = idd & 7;
        *(uint4*)(aob + (size_t)rl * 512 + part * 8) = *(const uint4*)(ols + rl * 80 + part * 8);
    }

    // ---- producer/consumer handoff: wait for all 8 heads of (b, i0), then conv_out ------
    int g = b * 8 + (i0 >> 7);
    __threadfence();                       // write back this block's ao slice (agent scope)
    __syncthreads();                       // all threads fenced before signaling
    if (tid == 0) {
        atomicAdd(&cnt[g], 1);
        while (__hip_atomic_load(&cnt[g], __ATOMIC_ACQUIRE, __HIP_MEMORY_SCOPE_AGENT) < 8)
            __builtin_amdgcn_s_sleep(8);
    }
    __syncthreads();
    __threadfence();                       // invalidate local caches before reading peers' ao

    // conv_out tile: m0 = i0 (128 n-rows), o0 = h*64
    {
        int m0 = i0, o0 = h * 64;
        ushort_t* als = smem;              // [128][32]
        ushort_t* bls = smem + 4096;       // [64][32]   (offsets in ushort units)
        int l15 = lane & 15, quad = lane >> 4;
        int wm = wave >> 1, wn = wave & 1;
        const ushort_t* A = ao + (size_t)b * 524288;

        f32x4 acc[4][2];
        #pragma unroll
        for (int ms = 0; ms < 4; ms++)
            #pragma unroll
            for (int ns = 0; ns < 2; ns++) acc[ms][ns] = (f32x4){0.f, 0.f, 0.f, 0.f};

        __syncthreads();
        for (int k0 = 0; k0 < 512; k0 += 32) {
            #pragma unroll
            for (int rep = 0; rep < 2; rep++) {
                int idd = rep * 256 + tid;
                int r = idd >> 2, part = idd & 3;
                int sw = part ^ ((r >> 2) & 3);
                cp16(A + (size_t)(m0 + r) * 512 + k0 + sw * 8, als + (size_t)idd * 8);
            }
            {
                int r = tid >> 2, part = tid & 3;
                int sw = part ^ ((r >> 2) & 3);
                cp16(wo + (size_t)(o0 + r) * 512 + k0 + sw * 8, bls + (size_t)tid * 8);
            }
            __syncthreads();
            bf16x8 af[4], bfr[2];
            #pragma unroll
            for (int ms = 0; ms < 4; ms++) {
                int row = wm * 64 + ms * 16 + l15;
                int slot = quad ^ ((row >> 2) & 3);
                af[ms] = *(const bf16x8*)(als + row * 32 + slot * 8);
            }
            #pragma unroll
            for (int ns = 0; ns < 2; ns++) {
                int row = wn * 32 + ns * 16 + l15;
                int slot = quad ^ ((row >> 2) & 3);
                bfr[ns] = *(const bf16x8*)(bls + row * 32 + slot * 8);
            }
            #pragma unroll
            for (int ms = 0; ms < 4; ms++)
                #pragma unroll
                for (int ns = 0; ns < 2; ns++)
                    acc[ms][ns] = __builtin_amdgcn_mfma_f32_16x16x32_bf16(af[ms], bfr[ns], acc[ms][ns], 0, 0, 0);
            __syncthreads();
        }

        #pragma unroll
        for (int ns = 0; ns < 2; ns++) {
            int o = o0 + wn * 32 + ns * 16 + l15;
            float bb = bo[o];
            #pragma unroll
            for (int ms = 0; ms < 4; ms++) {
                int n = m0 + wm * 64 + ms * 16 + quad * 4;
                size_t ga = ((size_t)(b * 512 + o)) * 1024 + n;
                float4 xv = *(const float4*)(xres + ga);
                float4 c4;
                c4.x = acc[ms][ns][0] + bb + xv.x;
                c4.y = acc[ms][ns][1] + bb + xv.y;
                c4.z = acc[ms][ns][2] + bb + xv.z;
                c4.w = acc[ms][ns][3] + bb + xv.w;
                *(float4*)(out + ga) = c4;
            }
        }
    }
}

extern "C" void kernel_launch(void* const* d_in, const int* in_sizes, int n_in,
                              void* d_out, int out_size, void* d_ws, size_t ws_size,
                              hipStream_t stream) {
    const float* x    = (const float*)d_in[0];
    const float* gn_w = (const float*)d_in[1];
    const float* gn_b = (const float*)d_in[2];
    const float* wq   = (const float*)d_in[3];
    const float* bq   = (const float*)d_in[4];
    const float* wk   = (const float*)d_in[5];
    const float* bk   = (const float*)d_in[6];
    const float* wv   = (const float*)d_in[7];
    const float* bv   = (const float*)d_in[8];
    const float* wo   = (const float*)d_in[9];
    const float* bo   = (const float*)d_in[10];

    char* ws = (char*)d_ws;
    ushort_t* xnt  = (ushort_t*)(ws);                        // 8 MB  [b][n][c]
    ushort_t* qt   = (ushort_t*)(ws + (((size_t)8)  << 20)); // 8 MB  [bh][n][d] (pre-scaled)
    ushort_t* kt   = (ushort_t*)(ws + (((size_t)16) << 20)); // 8 MB  [bh][n][d]
    ushort_t* vt   = (ushort_t*)(ws + (((size_t)24) << 20)); // 8 MB  [b][c][n]
    ushort_t* wbf  = (ushort_t*)(ws + (((size_t)32) << 20)); // 2 MB  Wq|Wk|Wv|Wo bf16
    int*      cnt  = (int*)     (ws + (((size_t)35) << 20)); // 256 B group counters
    ushort_t* ao   = xnt;   // attn output reuses xnt

    prep_gn<<<1280, 256, 0, stream>>>(x, gn_w, gn_b, wq, wk, wv, wo, wbf, xnt, cnt);

    conv_qkv<<<dim3(8, 24, 8), 256, 0, stream>>>(xnt, wbf, bq, bk, bv, qt, kt, vt);

    attn_out<<<512, 256, 0, stream>>>(qt, kt, vt, ao, wbf + 786432, bo, x, (float*)d_out, cnt);
}

// Round 15
// 155.076 us; speedup vs baseline: 3.2763x; 1.7322x over previous
//
#include <hip/hip_runtime.h>
#include <hip/hip_bf16.h>

typedef unsigned short ushort_t;
typedef __bf16 bf16_t;
typedef bf16_t bf16x8 __attribute__((ext_vector_type(8)));
typedef float f32x4 __attribute__((ext_vector_type(4)));
typedef float f32x16 __attribute__((ext_vector_type(16)));

#define CH 512
#define NSP 1024  // H*W

__device__ __forceinline__ float bf2f(ushort_t u) {
    union { unsigned int i; float f; } t; t.i = ((unsigned int)u) << 16; return t.f;
}
__device__ __forceinline__ ushort_t f2bf(float f) {
    union { float fl; unsigned int i; } t; t.fl = f;
    unsigned int r = t.i + 0x7fffu + ((t.i >> 16) & 1u);  // RNE
    return (ushort_t)(r >> 16);
}
// packed RNE f32x2 -> bf16x2 (v_cvt_pk_bf16_f32 on gfx950)
__device__ __forceinline__ unsigned int pk2(float a, float b) {
    __hip_bfloat162 h = __float22bfloat162_rn(make_float2(a, b));
    union { __hip_bfloat162 h2; unsigned int u; } t; t.h2 = h; return t.u;
}

#if __has_builtin(__builtin_amdgcn_global_load_lds)
#define HAVE_ASYNC_LDS 1
#endif
__device__ __forceinline__ void cp16(const ushort_t* g, ushort_t* l) {
#ifdef HAVE_ASYNC_LDS
    __builtin_amdgcn_global_load_lds((const __attribute__((address_space(1))) unsigned int*)g,
                                     (__attribute__((address_space(3))) unsigned int*)l, 16, 0, 0);
#else
    *(uint4*)l = *(const uint4*)g;
#endif
}

#if __has_builtin(__builtin_amdgcn_exp2f)
#define EXP2(x) __builtin_amdgcn_exp2f(x)
#else
#define EXP2(x) exp2f(x)
#endif

#define QSCALE 0.18033688011112042f   // 0.125 * log2(e), folded into q

// ---------------- prep_gn: blocks 0..255 = fused GroupNorm; 256..1279 = W fp32->bf16 ------
// (merged to cut one kernel launch; the two halves are independent)
__global__ __launch_bounds__(256) void prep_gn(const float* __restrict__ x, const float* __restrict__ gw,
                                               const float* __restrict__ gbias,
                                               const float* __restrict__ w0, const float* __restrict__ w1,
                                               const float* __restrict__ w2, const float* __restrict__ w3,
                                               ushort_t* __restrict__ wbf, ushort_t* __restrict__ xnt) {
    int tid = threadIdx.x;
    if (blockIdx.x >= 256) {
        int idx = (blockIdx.x - 256) * 256 + tid;   // 0..262143 float4s
        int my = idx >> 16;
        const float* src = (my == 0) ? w0 : (my == 1) ? w1 : (my == 2) ? w2 : w3;
        float4 v = reinterpret_cast<const float4*>(src)[idx & 65535];
        uint2 u = make_uint2(pk2(v.x, v.y), pk2(v.z, v.w));
        reinterpret_cast<uint2*>(wbf + (size_t)my * 262144)[idx & 65535] = u;
        return;
    }
    __shared__ float red[8];
    int bg = blockIdx.x;            // b*32+g
    int b = bg >> 5, g = bg & 31;
    const float4* x4 = reinterpret_cast<const float4*>(x + (size_t)bg * 16384);
    float4 v[16];
    float s = 0.f, s2 = 0.f;
    #pragma unroll
    for (int i = 0; i < 16; i++) {
        v[i] = x4[i * 256 + tid];
        s  += v[i].x + v[i].y + v[i].z + v[i].w;
        s2 += v[i].x * v[i].x + v[i].y * v[i].y + v[i].z * v[i].z + v[i].w * v[i].w;
    }
    #pragma unroll
    for (int off = 32; off > 0; off >>= 1) {
        s  += __shfl_down(s, off, 64);
        s2 += __shfl_down(s2, off, 64);
    }
    int wv = tid >> 6;
    if ((tid & 63) == 0) { red[wv] = s; red[4 + wv] = s2; }
    __syncthreads();
    float ts  = red[0] + red[1] + red[2] + red[3];
    float ts2 = red[4] + red[5] + red[6] + red[7];
    float mu  = ts * (1.f / 16384.f);
    float var = ts2 * (1.f / 16384.f) - mu * mu;
    float rstd = rsqrtf(var + 1e-5f);
    float ca[16], cb[16];
    #pragma unroll
    for (int cc = 0; cc < 16; cc++) {
        float ww = gw[g * 16 + cc], bb = gbias[g * 16 + cc];
        ca[cc] = rstd * ww; cb[cc] = bb - mu * ca[cc];
    }
    #pragma unroll
    for (int jj = 0; jj < 4; jj++) {
        float e[16];
        #pragma unroll
        for (int cc = 0; cc < 16; cc++) {
            float xv = (jj == 0) ? v[cc].x : (jj == 1) ? v[cc].y : (jj == 2) ? v[cc].z : v[cc].w;
            e[cc] = xv * ca[cc] + cb[cc];
        }
        uint4 u0 = make_uint4(pk2(e[0], e[1]), pk2(e[2], e[3]), pk2(e[4], e[5]), pk2(e[6], e[7]));
        uint4 u1 = make_uint4(pk2(e[8], e[9]), pk2(e[10], e[11]), pk2(e[12], e[13]), pk2(e[14], e[15]));
        ushort_t* dst = xnt + ((size_t)(b * 1024 + 4 * tid + jj)) * 512 + g * 16;
        *reinterpret_cast<uint4*>(dst)     = u0;
        *reinterpret_cast<uint4*>(dst + 8) = u1;
    }
}

// ---------------- Fused QKV conv (R1 v1): C[n_sp(128)][o(64)] tiles -----------------------
__global__ __launch_bounds__(256) void conv_qkv(const ushort_t* __restrict__ xnt,
                                                const ushort_t* __restrict__ wbf,
                                                const float* __restrict__ bq,
                                                const float* __restrict__ bk,
                                                const float* __restrict__ bv,
                                                ushort_t* __restrict__ qt,
                                                ushort_t* __restrict__ kt,
                                                ushort_t* __restrict__ vt) {
    __shared__ __align__(16) char smem[17408];
    ushort_t* als = (ushort_t*)smem;           // [128][32]
    ushort_t* bls = (ushort_t*)(smem + 8192);  // [64][32]
    int tid = threadIdx.x;
    int wave = tid >> 6, lane = tid & 63, l15 = lane & 15, quad = lane >> 4;
    int wm = wave >> 1, wn = wave & 1;
    int m0 = blockIdx.x * 128, o0 = blockIdx.y * 64, b = blockIdx.z;
    const ushort_t* A = xnt + (size_t)b * 524288;

    f32x4 acc[4][2];
    #pragma unroll
    for (int ms = 0; ms < 4; ms++)
        #pragma unroll
        for (int ns = 0; ns < 2; ns++) acc[ms][ns] = (f32x4){0.f, 0.f, 0.f, 0.f};

    for (int k0 = 0; k0 < 512; k0 += 32) {
        #pragma unroll
        for (int rep = 0; rep < 2; rep++) {
            int id = rep * 256 + tid;
            int r = id >> 2, part = id & 3;
            int sw = part ^ ((r >> 2) & 3);
            cp16(A + (size_t)(m0 + r) * 512 + k0 + sw * 8, als + (size_t)id * 8);
        }
        {
            int r = tid >> 2, part = tid & 3;
            int sw = part ^ ((r >> 2) & 3);
            cp16(wbf + (size_t)(o0 + r) * 512 + k0 + sw * 8, bls + (size_t)tid * 8);
        }
        __syncthreads();
        bf16x8 af[4], bfr[2];
        #pragma unroll
        for (int ms = 0; ms < 4; ms++) {
            int row = wm * 64 + ms * 16 + l15;
            int slot = quad ^ ((row >> 2) & 3);
            af[ms] = *(const bf16x8*)(als + row * 32 + slot * 8);
        }
        #pragma unroll
        for (int ns = 0; ns < 2; ns++) {
            int row = wn * 32 + ns * 16 + l15;
            int slot = quad ^ ((row >> 2) & 3);
            bfr[ns] = *(const bf16x8*)(bls + row * 32 + slot * 8);
        }
        #pragma unroll
        for (int ms = 0; ms < 4; ms++)
            #pragma unroll
            for (int ns = 0; ns < 2; ns++)
                acc[ms][ns] = __builtin_amdgcn_mfma_f32_16x16x32_bf16(af[ms], bfr[ns], acc[ms][ns], 0, 0, 0);
        __syncthreads();
    }

    int seg = o0 >> 9, lo = o0 & 511;
    if (seg < 2) {
        const float* bias = seg ? bk : bq;
        ushort_t* dst = seg ? kt : qt;
        float s = seg ? 1.f : QSCALE;
        float bv0 = bias[lo + wn * 32 + l15];
        float bv1 = bias[lo + wn * 32 + 16 + l15];
        ushort_t* cls = (ushort_t*)smem;   // [128 n][64 o]
        #pragma unroll
        for (int ms = 0; ms < 4; ms++)
            #pragma unroll
            for (int ns = 0; ns < 2; ns++) {
                float bb = ns ? bv1 : bv0;
                int idx = (wm * 64 + ms * 16 + quad * 4) * 64 + wn * 32 + ns * 16 + l15;
                unsigned int ua = pk2((acc[ms][ns][0] + bb) * s, (acc[ms][ns][1] + bb) * s);
                unsigned int ub = pk2((acc[ms][ns][2] + bb) * s, (acc[ms][ns][3] + bb) * s);
                cls[idx]       = (ushort_t)(ua & 0xffff);
                cls[idx + 64]  = (ushort_t)(ua >> 16);
                cls[idx + 128] = (ushort_t)(ub & 0xffff);
                cls[idx + 192] = (ushort_t)(ub >> 16);
            }
        __syncthreads();
        int h = lo >> 6;
        size_t obase = ((size_t)(b * 8 + h) * 1024 + m0) * 64;
        #pragma unroll
        for (int rep = 0; rep < 4; rep++) {
            int id = rep * 256 + tid;
            int r = id >> 3, part = id & 7;
            *(uint4*)(dst + obase + (size_t)r * 64 + part * 8) = *(const uint4*)(cls + r * 64 + part * 8);
        }
    } else {
        float bv0 = bv[lo + wn * 32 + l15];
        float bv1 = bv[lo + wn * 32 + 16 + l15];
        ushort_t* clst = (ushort_t*)smem;  // [64 o][136] transposed
        #pragma unroll
        for (int ms = 0; ms < 4; ms++)
            #pragma unroll
            for (int ns = 0; ns < 2; ns++) {
                float bb = ns ? bv1 : bv0;
                unsigned int ua = pk2(acc[ms][ns][0] + bb, acc[ms][ns][1] + bb);
                unsigned int ub = pk2(acc[ms][ns][2] + bb, acc[ms][ns][3] + bb);
                *(uint2*)(&clst[(wn * 32 + ns * 16 + l15) * 136 + wm * 64 + ms * 16 + quad * 4]) =
                    make_uint2(ua, ub);
            }
        __syncthreads();
        #pragma unroll
        for (int rep = 0; rep < 4; rep++) {
            int id = rep * 256 + tid;
            int row = id >> 4, part = id & 15;
            *(uint4*)(vt + ((size_t)(b * 512 + lo + row) * 1024 + m0 + part * 8)) =
                *(const uint4*)(clst + row * 136 + part * 8);
        }
    }
}

// ---------------- MFMA flash attention v7 (R10): counted-vmcnt deep pipeline --------------
#define Z16 {0.f,0.f,0.f,0.f,0.f,0.f,0.f,0.f,0.f,0.f,0.f,0.f,0.f,0.f,0.f,0.f}

#define PV_STEP(JS, P) {                                                                     \
    unsigned wA0 = pk2(P[((JS)&1)*8+0], P[((JS)&1)*8+1]);                                    \
    unsigned wA1 = pk2(P[((JS)&1)*8+2], P[((JS)&1)*8+3]);                                    \
    unsigned wB0 = pk2(P[((JS)&1)*8+4], P[((JS)&1)*8+5]);                                    \
    unsigned wB1 = pk2(P[((JS)&1)*8+6], P[((JS)&1)*8+7]);                                    \
    asm("v_permlane32_swap_b32 %0, %1" : "+v"(wA0), "+v"(wB0));                              \
    asm("v_permlane32_swap_b32 %0, %1" : "+v"(wA1), "+v"(wB1));                              \
    union { unsigned u[4]; bf16x8 v; } pa_;                                                  \
    pa_.u[0] = wA0; pa_.u[1] = wA1; pa_.u[2] = wB0; pa_.u[3] = wB1;                          \
    int phys_ = (((JS) * 2) | hi) ^ r7;                                                      \
    bf16x8 vf0 = *(const bf16x8*)(vbuf + l31 * 64 + phys_ * 8);                              \
    bf16x8 vf1 = *(const bf16x8*)(vbuf + (32 + l31) * 64 + phys_ * 8);                       \
    __builtin_amdgcn_s_setprio(1);                                                           \
    vacc0 = __builtin_amdgcn_mfma_f32_32x32x16_bf16(pa_.v, vf0, vacc0, 0, 0, 0);             \
    vacc1 = __builtin_amdgcn_mfma_f32_32x32x16_bf16(pa_.v, vf1, vacc1, 0, 0, 0);             \
    __builtin_amdgcn_s_setprio(0); }

__global__ __launch_bounds__(256) void attn_kernel(const ushort_t* __restrict__ qt,
                                                   const ushort_t* __restrict__ kt,
                                                   const ushort_t* __restrict__ vt,
                                                   ushort_t* __restrict__ ao) {
    __shared__ __align__(16) ushort_t smem[24576];   // 48 KB: K[3][4096] | V[3][4096]
    int tid = threadIdx.x;
    int wave = tid >> 6, lane = tid & 63, l31 = lane & 31, hi = lane >> 5;
    int id = blockIdx.x;                 // 512 blocks: XCD-swizzled, 8 i-tiles of a bh per XCD
    int bh = (id & 7) * 8 + (id >> 6);
    int i0 = ((id >> 3) & 7) * 128;
    const ushort_t* qb = qt + (size_t)bh * 65536;
    const ushort_t* kb = kt + (size_t)bh * 65536;
    const ushort_t* vb = vt + (size_t)bh * 65536;
    int iw0 = i0 + wave * 32;
    int r7 = l31 & 7;

    bf16x8 qf[4];
    #pragma unroll
    for (int ks = 0; ks < 4; ks++)
        qf[ks] = *(const bf16x8*)(qb + (size_t)(iw0 + l31) * 64 + ks * 16 + hi * 8);

    f32x16 vacc0 = Z16, vacc1 = Z16;
    float lacc = 0.f;

    int rk0 = tid >> 3, sk = tid & 7, rk1 = rk0 + 32;
    const ushort_t* kg0 = kb + rk0 * 64 + (sk ^ (rk0 & 7)) * 8;
    const ushort_t* kg1 = kb + rk1 * 64 + (sk ^ (rk1 & 7)) * 8;
    const ushort_t* vg0 = vb + (size_t)rk0 * 1024 + (sk ^ (rk0 & 7)) * 8;
    const ushort_t* vg1 = vb + (size_t)rk1 * 1024 + (sk ^ (rk1 & 7)) * 8;

    // prologue: tile 0 -> buf0, tile 1 -> buf1 (8 loads in flight)
    cp16(kg0, smem + tid * 8);
    cp16(kg1, smem + (tid + 256) * 8);
    cp16(vg0, smem + 12288 + tid * 8);
    cp16(vg1, smem + 12288 + (tid + 256) * 8);
    kg0 += 4096; kg1 += 4096; vg0 += 64; vg1 += 64;
    cp16(kg0, smem + 4096 + tid * 8);
    cp16(kg1, smem + 4096 + (tid + 256) * 8);
    cp16(vg0, smem + 16384 + tid * 8);
    cp16(vg1, smem + 16384 + (tid + 256) * 8);
    kg0 += 4096; kg1 += 4096; vg0 += 64; vg1 += 64;

    for (int jt = 0; jt < 16; jt++) {
        // tile jt's 4 loads complete; tile jt+1's 4 remain in flight across the barrier
        if (jt == 15) asm volatile("s_waitcnt vmcnt(0)" ::: "memory");
        else          asm volatile("s_waitcnt vmcnt(4)" ::: "memory");
        __builtin_amdgcn_s_barrier();
        __builtin_amdgcn_sched_barrier(0);
        if (jt < 14) {
            int nb = jt + 2 - ((jt + 2) >= 3 ? 3 : 0) - ((jt + 2) >= 6 ? 3 : 0)
                     - ((jt + 2) >= 9 ? 3 : 0) - ((jt + 2) >= 12 ? 3 : 0) - ((jt + 2) >= 15 ? 3 : 0);
            ushort_t* kd = smem + nb * 4096;
            ushort_t* vd = smem + 12288 + nb * 4096;
            cp16(kg0, kd + tid * 8);
            cp16(kg1, kd + (tid + 256) * 8);
            cp16(vg0, vd + tid * 8);
            cp16(vg1, vd + (tid + 256) * 8);
            kg0 += 4096; kg1 += 4096; vg0 += 64; vg1 += 64;
        }
        int cur = jt - (jt >= 3 ? 3 : 0) - (jt >= 6 ? 3 : 0) - (jt >= 9 ? 3 : 0)
                  - (jt >= 12 ? 3 : 0) - (jt >= 15 ? 3 : 0);
        const ushort_t* kbuf = smem + cur * 4096;
        const ushort_t* vbuf = smem + 12288 + cur * 4096;

        f32x16 s0 = Z16, s1 = Z16;
        __builtin_amdgcn_s_setprio(1);
        #pragma unroll
        for (int ks = 0; ks < 4; ks++) {
            int phys = ((ks * 2) | hi) ^ r7;
            bf16x8 kf = *(const bf16x8*)(kbuf + l31 * 64 + phys * 8);
            s0 = __builtin_amdgcn_mfma_f32_32x32x16_bf16(kf, qf[ks], s0, 0, 0, 0);
        }
        #pragma unroll
        for (int ks = 0; ks < 4; ks++) {
            int phys = ((ks * 2) | hi) ^ r7;
            bf16x8 kf = *(const bf16x8*)(kbuf + (32 + l31) * 64 + phys * 8);
            s1 = __builtin_amdgcn_mfma_f32_32x32x16_bf16(kf, qf[ks], s1, 0, 0, 0);
        }
        __builtin_amdgcn_s_setprio(0);

        float p0[16], p1[16];
        #pragma unroll
        for (int r = 0; r < 16; r++) p0[r] = EXP2(s0[r]);
        #pragma unroll
        for (int r = 0; r < 16; r++) p1[r] = EXP2(s1[r]);
        float t0 = 0.f, t1 = 0.f, t2 = 0.f, t3 = 0.f;
        #pragma unroll
        for (int r = 0; r < 4; r++) { t0 += p0[r]; t1 += p0[4 + r]; t2 += p0[8 + r]; t3 += p0[12 + r]; }
        #pragma unroll
        for (int r = 0; r < 4; r++) { t0 += p1[r]; t1 += p1[4 + r]; t2 += p1[8 + r]; t3 += p1[12 + r]; }
        lacc += (t0 + t1) + (t2 + t3);

        PV_STEP(0, p0)
        PV_STEP(1, p0)
        PV_STEP(2, p1)
        PV_STEP(3, p1)
    }

    __syncthreads();   // all waves done reading LDS buffers before epilogue reuse

    lacc += __shfl_xor(lacc, 32, 64);
    float linv[16];
    #pragma unroll
    for (int r = 0; r < 16; r++) {
        int ir = (r & 3) + 8 * (r >> 2) + 4 * hi;
        linv[r] = 1.f / __shfl(lacc, ir, 64);
    }

    ushort_t* ols = smem;
    #pragma unroll
    for (int r = 0; r < 16; r++) {
        int irow = wave * 32 + (r & 3) + 8 * (r >> 2) + 4 * hi;
        ols[irow * 80 + l31]      = f2bf(vacc0[r] * linv[r]);
        ols[irow * 80 + 32 + l31] = f2bf(vacc1[r] * linv[r]);
    }
    __syncthreads();
    int b = bh >> 3, h = bh & 7;
    ushort_t* aob = ao + ((size_t)b * 1024 + i0) * 512 + h * 64;
    #pragma unroll
    for (int rep = 0; rep < 4; rep++) {
        int idd = rep * 256 + tid;
        int rl = idd >> 3, part = idd & 7;
        *(uint4*)(aob + (size_t)rl * 512 + part * 8) = *(const uint4*)(ols + rl * 80 + part * 8);
    }
}

// ---------------- Final conv v3: 128(n) x 64(o), direct register epilogue, 2 blocks/CU ----
__global__ __launch_bounds__(256) void conv_out(const ushort_t* __restrict__ ao,
                                                const ushort_t* __restrict__ wo,
                                                const float* __restrict__ bo,
                                                const float* __restrict__ xres,
                                                float* __restrict__ out) {
    __shared__ __align__(16) char smem[12288];
    ushort_t* als = (ushort_t*)smem;           // [128][32] (ao rows n)
    ushort_t* bls = (ushort_t*)(smem + 8192);  // [64][32]  (wo rows o)
    int tid = threadIdx.x;
    int wave = tid >> 6, lane = tid & 63, l15 = lane & 15, quad = lane >> 4;
    int wm = wave >> 1, wn = wave & 1;
    int m0 = blockIdx.x * 128, o0 = blockIdx.y * 64, b = blockIdx.z;
    const ushort_t* A = ao + (size_t)b * 524288;

    f32x4 acc[4][2];
    #pragma unroll
    for (int ms = 0; ms < 4; ms++)
        #pragma unroll
        for (int ns = 0; ns < 2; ns++) acc[ms][ns] = (f32x4){0.f, 0.f, 0.f, 0.f};

    for (int k0 = 0; k0 < 512; k0 += 32) {
        #pragma unroll
        for (int rep = 0; rep < 2; rep++) {
            int id = rep * 256 + tid;
            int r = id >> 2, part = id & 3;
            int sw = part ^ ((r >> 2) & 3);
            cp16(A + (size_t)(m0 + r) * 512 + k0 + sw * 8, als + (size_t)id * 8);
        }
        {
            int r = tid >> 2, part = tid & 3;
            int sw = part ^ ((r >> 2) & 3);
            cp16(wo + (size_t)(o0 + r) * 512 + k0 + sw * 8, bls + (size_t)tid * 8);
        }
        __syncthreads();
        bf16x8 af[4], bfr[2];
        #pragma unroll
        for (int ms = 0; ms < 4; ms++) {
            int row = wm * 64 + ms * 16 + l15;
            int slot = quad ^ ((row >> 2) & 3);
            af[ms] = *(const bf16x8*)(als + row * 32 + slot * 8);
        }
        #pragma unroll
        for (int ns = 0; ns < 2; ns++) {
            int row = wn * 32 + ns * 16 + l15;
            int slot = quad ^ ((row >> 2) & 3);
            bfr[ns] = *(const bf16x8*)(bls + row * 32 + slot * 8);
        }
        #pragma unroll
        for (int ms = 0; ms < 4; ms++)
            #pragma unroll
            for (int ns = 0; ns < 2; ns++)
                acc[ms][ns] = __builtin_amdgcn_mfma_f32_16x16x32_bf16(af[ms], bfr[ns], acc[ms][ns], 0, 0, 0);
        __syncthreads();
    }

    #pragma unroll
    for (int ns = 0; ns < 2; ns++) {
        int o = o0 + wn * 32 + ns * 16 + l15;
        float bb = bo[o];
        #pragma unroll
        for (int ms = 0; ms < 4; ms++) {
            int n = m0 + wm * 64 + ms * 16 + quad * 4;
            size_t ga = ((size_t)(b * 512 + o)) * 1024 + n;
            float4 xv = *(const float4*)(xres + ga);
            float4 c4;
            c4.x = acc[ms][ns][0] + bb + xv.x;
            c4.y = acc[ms][ns][1] + bb + xv.y;
            c4.z = acc[ms][ns][2] + bb + xv.z;
            c4.w = acc[ms][ns][3] + bb + xv.w;
            *(float4*)(out + ga) = c4;
        }
    }
}

extern "C" void kernel_launch(void* const* d_in, const int* in_sizes, int n_in,
                              void* d_out, int out_size, void* d_ws, size_t ws_size,
                              hipStream_t stream) {
    const float* x    = (const float*)d_in[0];
    const float* gn_w = (const float*)d_in[1];
    const float* gn_b = (const float*)d_in[2];
    const float* wq   = (const float*)d_in[3];
    const float* bq   = (const float*)d_in[4];
    const float* wk   = (const float*)d_in[5];
    const float* bk   = (const float*)d_in[6];
    const float* wv   = (const float*)d_in[7];
    const float* bv   = (const float*)d_in[8];
    const float* wo   = (const float*)d_in[9];
    const float* bo   = (const float*)d_in[10];

    char* ws = (char*)d_ws;
    ushort_t* xnt  = (ushort_t*)(ws);                        // 8 MB  [b][n][c]
    ushort_t* qt   = (ushort_t*)(ws + (((size_t)8)  << 20)); // 8 MB  [bh][n][d] (pre-scaled)
    ushort_t* kt   = (ushort_t*)(ws + (((size_t)16) << 20)); // 8 MB  [bh][n][d]
    ushort_t* vt   = (ushort_t*)(ws + (((size_t)24) << 20)); // 8 MB  [b][c][n]
    ushort_t* wbf  = (ushort_t*)(ws + (((size_t)32) << 20)); // 2 MB  Wq|Wk|Wv|Wo bf16
    ushort_t* ao   = xnt;   // attn output reuses xnt

    prep_gn<<<1280, 256, 0, stream>>>(x, gn_w, gn_b, wq, wk, wv, wo, wbf, xnt);

    conv_qkv<<<dim3(8, 24, 8), 256, 0, stream>>>(xnt, wbf, bq, bk, bv, qt, kt, vt);

    attn_kernel<<<512, 256, 0, stream>>>(qt, kt, vt, ao);

    conv_out<<<dim3(8, 8, 8), 256, 0, stream>>>(ao, wbf + 786432, bo, x, (float*)d_out);
}